// Round 3
// baseline (186.873 us; speedup 1.0000x reference)
//
#include <hip/hip_runtime.h>
#include <hip/hip_bf16.h>

#define SEQ 2048
#define DMODEL 1024
#define NHEAD 16
#define HDIM 64
#define DPOS 64
#define BATCH 2

constexpr float EVENT_HORIZON = 1e-6f;
constexpr float MAX_FORCE = 50.0f;
constexpr float CURV = 0.15f;
constexpr float LOG2E = 1.44269504f;
// P = exp2(min(f,50)*log2e - S2), S2 = 39*log2e: e <= 2^15.87 = 59847 (fp16-safe),
// ratio-invariant under softmax normalization.
constexpr float SHIFT = 39.0f;

typedef __attribute__((ext_vector_type(8))) short frag8;        // 8 bf16/ushort
typedef __attribute__((ext_vector_type(4))) unsigned int uint4v;
typedef __attribute__((ext_vector_type(8))) _Float16 half8;     // 8 fp16
typedef __attribute__((ext_vector_type(2))) _Float16 half2t;    // 2 fp16
typedef __attribute__((ext_vector_type(4))) float frag4f;       // 4 fp32 (C/D)

union A8u { half8 v; half2t h[4]; };

__device__ inline short bfbits(float f) {
  __hip_bfloat16 h = __float2bfloat16(f);
  return *reinterpret_cast<short*>(&h);
}
__device__ inline float fbits(unsigned u) {
  union { unsigned u; float f; } c; c.u = u; return c.f;
}
__device__ inline half2t pkrtz(float a, float b) {
  return __builtin_bit_cast(half2t, __builtin_amdgcn_cvt_pkrtz(a, b));
}
// native 2^x, single v_exp_f32 (no hidden *log2e mul like __expf)
__device__ inline float exp2_fast(float x) {
  float r;
  asm("v_exp_f32 %0, %1" : "=v"(r) : "v"(x));
  return r;
}
// XOR swizzle in 16B units: row = 8 units (128B); b128 frag reads (fixed unit,
// 16 consecutive rows) and staging writes both cover banks <=2-way (free).
__device__ inline int swz(int row, int u) { return row * 8 + (u ^ (row & 7)); }

// ---------------------------------------------------------------------------
// Prep A (fused): transpose x -> xt[bh][d][j] fp16 AND masses[bh][s] =
// softplus(dot(x_row, W_mass[h])).
// ---------------------------------------------------------------------------
__global__ __launch_bounds__(256) void prep_xt_masses(
    const float* __restrict__ x, const float* __restrict__ Wm,
    _Float16* __restrict__ xt, float* __restrict__ masses) {
  int bh = blockIdx.x;           // b*16+h
  int h = bh & 15, b = bh >> 4;
  int t = threadIdx.x;
  int d = t & 63;
  int jg = (t >> 6) + (blockIdx.y << 2);   // j-group of 8, 0..255
  int j0 = jg * 8;
  const float* src = x + (size_t)(b * SEQ) * DMODEL + h * HDIM + d;
  float wmd = Wm[h * HDIM + d];
  half8 v;
  float fv[8];
#pragma unroll
  for (int jj = 0; jj < 8; ++jj) {
    float f = src[(size_t)(j0 + jj) * DMODEL];
    fv[jj] = f;
    v[jj] = (_Float16)f;
  }
  *(half8*)(xt + ((size_t)bh * HDIM + d) * SEQ + j0) = v;

  float msum = 0.f;
#pragma unroll
  for (int jj = 0; jj < 8; ++jj) {
    float s = fv[jj] * wmd;
#pragma unroll
    for (int off = 32; off; off >>= 1) s += __shfl_xor(s, off, 64);
    if (d == jj) msum = s;      // lane jj keeps row j0+jj's dot
  }
  if (d < 8) {
    float m = (msum > 20.f) ? msum : log1pf(expf(msum));
    masses[(size_t)bh * SEQ + j0 + d] = m;
  }
}

// ---------------------------------------------------------------------------
// Prep B: Wout fp32 -> fp16.
// ---------------------------------------------------------------------------
__global__ __launch_bounds__(256) void prep_wh(
    const float* __restrict__ Wout, _Float16* __restrict__ wh) {
  int i = blockIdx.x * 256 + threadIdx.x;
  float4 v = ((const float4*)Wout)[i];
  _Float16 o[4] = {(_Float16)v.x, (_Float16)v.y, (_Float16)v.z, (_Float16)v.w};
  *(float2*)(wh + 4 * (size_t)i) = *(float2*)o;
}

// ---------------------------------------------------------------------------
// Kernel 2: LDS-tiled distance kernel, bf16 output.
// ---------------------------------------------------------------------------
__global__ __launch_bounds__(256) void invdist_kernel(
    const float* __restrict__ pos, unsigned short* __restrict__ invd) {
  __shared__ float Li[64 * 68];
  __shared__ float Lj[64 * 68];
  int t = threadIdx.x;
  int i0 = blockIdx.y * 64, j0 = blockIdx.x * 64;

  int kk = (t & 15) * 4;
  int rr = t >> 4;
#pragma unroll
  for (int q = 0; q < 4; ++q) {
    int row = q * 16 + rr;
    float4 a = *(const float4*)(pos + (size_t)(i0 + row) * DPOS + kk);
    float4 b = *(const float4*)(pos + (size_t)(j0 + row) * DPOS + kk);
    Li[(kk + 0) * 68 + row] = a.x; Li[(kk + 1) * 68 + row] = a.y;
    Li[(kk + 2) * 68 + row] = a.z; Li[(kk + 3) * 68 + row] = a.w;
    Lj[(kk + 0) * 68 + row] = b.x; Lj[(kk + 1) * 68 + row] = b.y;
    Lj[(kk + 2) * 68 + row] = b.z; Lj[(kk + 3) * 68 + row] = b.w;
  }
  __syncthreads();

  int ti = (t >> 4) * 4;
  int tj = (t & 15) * 4;

  float acc[4][4];
#pragma unroll
  for (int a = 0; a < 4; ++a)
#pragma unroll
    for (int b = 0; b < 4; ++b) acc[a][b] = 0.f;

#pragma unroll 8
  for (int k = 0; k < 64; ++k) {
    float4 a = *(const float4*)(&Li[k * 68 + ti]);
    float4 b = *(const float4*)(&Lj[k * 68 + tj]);
    float av[4] = {a.x, a.y, a.z, a.w};
    float bv[4] = {b.x, b.y, b.z, b.w};
#pragma unroll
    for (int mi = 0; mi < 4; ++mi)
#pragma unroll
      for (int mj = 0; mj < 4; ++mj) {
        float d = av[mi] - bv[mj];
        acc[mi][mj] += d * d;
      }
  }

#pragma unroll
  for (int mi = 0; mi < 4; ++mi) {
    ushort4 o;
    unsigned short* op = (unsigned short*)&o;
#pragma unroll
    for (int mj = 0; mj < 4; ++mj) {
      float d2 = acc[mi][mj];
      float dn = sqrtf(d2 + EVENT_HORIZON);
      float w = d2 * (1.f + CURV * __cosf(dn));
      op[mj] = (unsigned short)bfbits(1.0f / fmaxf(w, EVENT_HORIZON));
    }
    *(ushort4*)(&invd[(size_t)(i0 + ti + mi) * SEQ + j0 + tj]) = o;
  }
}

// ---------------------------------------------------------------------------
// Kernel 3: fused gravitational attention, fp16 MFMA PV.
// r3: j-split occupancy fix. Block = 64 i-rows, 8 waves = 4 i-pairs x 2
// j-halves; each wave sweeps 1024 j in 16 chunks of 64 j. Grid (32 bh,
// 32 i-blocks) = 1024 blocks = 4 blocks/CU (was grid-limited at 2), up to
// 32 waves/CU. Partial acc/accs of the two j-halves combine via LDS in the
// epilogue (split is exactly associative: fixed SHIFT, no running max).
// ---------------------------------------------------------------------------
__global__ __launch_bounds__(512, 8) void attn_mfma_kernel(
    const _Float16* __restrict__ xt, const float* __restrict__ masses,
    const unsigned short* __restrict__ invd, const float* __restrict__ G,
    _Float16* __restrict__ attnout) {
  __shared__ _Float16 Vs[2][2][64 * 64];   // [buf][jhalf], 8 KB each, swizzled
  __shared__ float Ms[2][2][64];           // [buf][jhalf][j] masses broadcast

  constexpr float S2 = SHIFT * LOG2E;                 // 56.265
  constexpr float C2 = (MAX_FORCE - SHIFT) * LOG2E;   // 15.870

  int bh = blockIdx.x;
  int h = bh & (NHEAD - 1), b = bh >> 4;
  int i0 = blockIdx.y * 64;
  int t = threadIdx.x, w = t >> 6, lane = t & 63;
  int l15 = lane & 15, quad = lane >> 4;
  int pair = w >> 1, jhalf = w & 1;
  int iw = i0 + pair * 16;

  float gabs = fabsf(G[h]);
  const float* mrow = masses + (size_t)bh * SEQ;
  float cm = gabs * mrow[iw + l15] * LOG2E;           // row scalar, log2 domain
  const unsigned short* ivrow =
      invd + (size_t)(iw + l15) * SEQ + jhalf * 1024;

  // staging role: thread t -> d-row t>>3, 16B-unit t&7 (stages BOTH halves)
  int srow = t >> 3, sunit = t & 7;
  const _Float16* srcrow =
      xt + ((size_t)bh * HDIM + srow) * SEQ + sunit * 8;
  int swzoff = swz(srow, sunit) * 8;

  half8 vone;
#pragma unroll
  for (int k = 0; k < 8; ++k) vone[k] = (_Float16)1.f;

  frag4f acc[4];
#pragma unroll
  for (int nt = 0; nt < 4; ++nt) acc[nt] = (frag4f)0.f;
  frag4f accs = (frag4f)0.f;          // row sums (every column identical)

  // ---- prologue: chunk 0 (j = 0..63 and 1024..1087) ----
  *(half8*)(&Vs[0][0][0] + swzoff) = *(const half8*)(srcrow);
  *(half8*)(&Vs[0][1][0] + swzoff) = *(const half8*)(srcrow + 1024);
  if (t < 128) Ms[0][t >> 6][t & 63] = mrow[(t >> 6) * 1024 + (t & 63)];
  frag8 iv_cur[2], iv_nxt[2];
  iv_cur[0] = *(const frag8*)(ivrow + quad * 8);
  iv_cur[1] = *(const frag8*)(ivrow + 32 + quad * 8);
  __syncthreads();

  for (int c = 0; c < 16; ++c) {
    // ---- issue prefetches for chunk c+1 ----
    half8 vpre0, vpre1;
    float mload = 0.f;
    if (c < 15) {
      int jn = (c + 1) * 64;
      vpre0 = *(const half8*)(srcrow + jn);
      vpre1 = *(const half8*)(srcrow + 1024 + jn);
      if (t < 128) mload = mrow[(t >> 6) * 1024 + jn + (t & 63)];
      iv_nxt[0] = *(const frag8*)(ivrow + jn + quad * 8);
      iv_nxt[1] = *(const frag8*)(ivrow + jn + 32 + quad * 8);
    }

    // ---- compute this wave's 64 j from buf[c&1][jhalf] ----
    const _Float16* Vbase = &Vs[c & 1][jhalf][0];
    const float* Mbase = &Ms[c & 1][jhalf][0];

#pragma unroll
    for (int kh = 0; kh < 2; ++kh) {
      // masses broadcast from LDS (same addr across l15 -> bank broadcast)
      const float* mp = Mbase + kh * 32 + quad * 8;
      float4 mjl = *(const float4*)(mp);
      float4 mjh = *(const float4*)(mp + 4);
      float mjf[8] = {mjl.x, mjl.y, mjl.z, mjl.w,
                      mjh.x, mjh.y, mjh.z, mjh.w};
      uint4v uv = __builtin_bit_cast(uint4v, iv_cur[kh]);
      float e[8];
#pragma unroll
      for (int p = 0; p < 4; ++p) {
        float ivA = fbits(uv[p] << 16);          // even j: low bf16
        float ivB = fbits(uv[p] & 0xffff0000u);  // odd j: high bf16
        float fA = fmaf(cm * mjf[2 * p], ivA, -S2);
        float fB = fmaf(cm * mjf[2 * p + 1], ivB, -S2);
        e[2 * p] = exp2_fast(fminf(fA, C2));
        e[2 * p + 1] = exp2_fast(fminf(fB, C2));
      }
      A8u A;
#pragma unroll
      for (int p = 0; p < 4; ++p)
        A.h[p] = pkrtz(e[2 * p], e[2 * p + 1]);

      __builtin_amdgcn_s_setprio(1);
      accs = __builtin_amdgcn_mfma_f32_16x16x32_f16(A.v, vone, accs, 0, 0, 0);
#pragma unroll
      for (int nt = 0; nt < 4; ++nt) {
        half8 Bf = *(const half8*)(Vbase + swz(nt * 16 + l15, kh * 4 + quad) * 8);
        acc[nt] = __builtin_amdgcn_mfma_f32_16x16x32_f16(A.v, Bf, acc[nt], 0, 0, 0);
      }
      __builtin_amdgcn_s_setprio(0);
    }

    // ---- rotate prefetches in; write V/M prefetch to other buffer ----
    if (c < 15) {
      _Float16* Vn = &Vs[(c + 1) & 1][0][0];
      *(half8*)(Vn + swzoff) = vpre0;
      *(half8*)(Vn + 4096 + swzoff) = vpre1;
      if (t < 128) Ms[(c + 1) & 1][t >> 6][t & 63] = mload;
      iv_cur[0] = iv_nxt[0]; iv_cur[1] = iv_nxt[1];
    }
    __syncthreads();
  }

  // ---- combine j-halves via LDS (reuse Vs; all compute is behind the
  // final loop barrier), then normalize + store ----
  float* Lf = (float*)&Vs[0][0][0];
  int cb = (pair * 64 + lane) * 24;    // 96 B stride: 16B-aligned b128s
  if (jhalf == 1) {
    *(frag4f*)(Lf + cb + 0)  = acc[0];
    *(frag4f*)(Lf + cb + 4)  = acc[1];
    *(frag4f*)(Lf + cb + 8)  = acc[2];
    *(frag4f*)(Lf + cb + 12) = acc[3];
    *(frag4f*)(Lf + cb + 16) = accs;
  }
  __syncthreads();
  if (jhalf == 0) {
    acc[0] += *(frag4f*)(Lf + cb + 0);
    acc[1] += *(frag4f*)(Lf + cb + 4);
    acc[2] += *(frag4f*)(Lf + cb + 8);
    acc[3] += *(frag4f*)(Lf + cb + 12);
    accs   += *(frag4f*)(Lf + cb + 16);
#pragma unroll
    for (int reg = 0; reg < 4; ++reg) {
      int r = quad * 4 + reg;            // C/D row within 16x16 tile
      float s = 1.f / accs[reg];
#pragma unroll
      for (int nt = 0; nt < 4; ++nt) {
        attnout[(size_t)(b * SEQ + iw + r) * DMODEL + h * HDIM + nt * 16 + l15] =
            (_Float16)(acc[nt][reg] * s);
      }
    }
  }
}

// ---------------------------------------------------------------------------
// Kernel 4: out = attnout @ wh^T via fp16 MFMA. r3: 64(M)x64(N) tile, BK=64,
// double-buffered swizzled LDS, one barrier per K-chunk. 4 waves, each
// 32m x 32n (2x2 frags). grid (16,64) = 1024 blocks = 4 blocks/CU (was 2).
// ---------------------------------------------------------------------------
__global__ __launch_bounds__(256) void out_gemm_mfma(
    const _Float16* __restrict__ Ag, const _Float16* __restrict__ Wg,
    float* __restrict__ C) {
  __shared__ _Float16 As[2][64 * 64];    // 8 KB each
  __shared__ _Float16 Bs[2][64 * 64];    // 8 KB each

  int t = threadIdx.x, w = t >> 6, lane = t & 63;
  int l15 = lane & 15, quad = lane >> 4;
  int m0 = blockIdx.y * 64, n0 = blockIdx.x * 64;
  int mh = (w & 1) * 32, nh = (w >> 1) * 32;

  int ar = t >> 2;  int au = (t & 3) * 2;   // row 0..63, units {au, au+1}
  const _Float16* abase = Ag + (size_t)(m0 + ar) * DMODEL + au * 8;
  const _Float16* bbase = Wg + (size_t)(n0 + ar) * DMODEL + au * 8;

  frag4f acc[2][2];
#pragma unroll
  for (int mt = 0; mt < 2; ++mt)
#pragma unroll
    for (int nt = 0; nt < 2; ++nt) acc[mt][nt] = (frag4f)0.f;

  half8 a0, a1, b0, b1;
  a0 = *(const half8*)(abase);      a1 = *(const half8*)(abase + 8);
  b0 = *(const half8*)(bbase);      b1 = *(const half8*)(bbase + 8);
  {
    _Float16* aw = As[0]; _Float16* bw = Bs[0];
    *(half8*)(aw + swz(ar, au + 0) * 8) = a0;
    *(half8*)(aw + swz(ar, au + 1) * 8) = a1;
    *(half8*)(bw + swz(ar, au + 0) * 8) = b0;
    *(half8*)(bw + swz(ar, au + 1) * 8) = b1;
  }
  __syncthreads();

  for (int kc = 0; kc < 16; ++kc) {
    if (kc < 15) {
      const _Float16* ap = abase + (kc + 1) * 64;
      const _Float16* bp = bbase + (kc + 1) * 64;
      a0 = *(const half8*)(ap);      a1 = *(const half8*)(ap + 8);
      b0 = *(const half8*)(bp);      b1 = *(const half8*)(bp + 8);
    }

    const _Float16* ac = As[kc & 1];
    const _Float16* bc = Bs[kc & 1];
#pragma unroll
    for (int kh = 0; kh < 2; ++kh) {
      half8 Af[2], Bf[2];
#pragma unroll
      for (int mt = 0; mt < 2; ++mt)
        Af[mt] = *(const half8*)(ac + swz(mh + mt * 16 + l15, kh * 4 + quad) * 8);
#pragma unroll
      for (int nt = 0; nt < 2; ++nt)
        Bf[nt] = *(const half8*)(bc + swz(nh + nt * 16 + l15, kh * 4 + quad) * 8);
#pragma unroll
      for (int mt = 0; mt < 2; ++mt)
#pragma unroll
        for (int nt = 0; nt < 2; ++nt)
          acc[mt][nt] = __builtin_amdgcn_mfma_f32_16x16x32_f16(Af[mt], Bf[nt], acc[mt][nt], 0, 0, 0);
    }

    if (kc < 15) {
      _Float16* aw = As[(kc + 1) & 1]; _Float16* bw = Bs[(kc + 1) & 1];
      *(half8*)(aw + swz(ar, au + 0) * 8) = a0;
      *(half8*)(aw + swz(ar, au + 1) * 8) = a1;
      *(half8*)(bw + swz(ar, au + 0) * 8) = b0;
      *(half8*)(bw + swz(ar, au + 1) * 8) = b1;
    }
    __syncthreads();
  }

#pragma unroll
  for (int mt = 0; mt < 2; ++mt)
#pragma unroll
    for (int nt = 0; nt < 2; ++nt)
#pragma unroll
      for (int reg = 0; reg < 4; ++reg) {
        int m = m0 + mh + mt * 16 + quad * 4 + reg;
        int n = n0 + nh + nt * 16 + l15;
        C[(size_t)m * DMODEL + n] = acc[mt][nt][reg];
      }
}

// ---------------------------------------------------------------------------
extern "C" void kernel_launch(void* const* d_in, const int* in_sizes, int n_in,
                              void* d_out, int out_size, void* d_ws, size_t ws_size,
                              hipStream_t stream) {
  const float* x    = (const float*)d_in[0];
  const float* pos  = (const float*)d_in[1];
  const float* Wm   = (const float*)d_in[2];
  const float* G    = (const float*)d_in[3];
  const float* Wout = (const float*)d_in[4];
  float* out = (float*)d_out;

  char* wsb = (char*)d_ws;
  float* masses = (float*)wsb;                                    // 256 KB
  unsigned short* invd = (unsigned short*)(wsb + (1 << 18));      // 8 MB
  _Float16* attnout = (_Float16*)(wsb + (1 << 18) + (8 << 20));   // 8 MB
  _Float16* xt      = (_Float16*)(wsb + (1 << 18) + (16 << 20));  // 8 MB
  _Float16* wh      = (_Float16*)(wsb + (1 << 18) + (24 << 20));  // 2 MB

  prep_xt_masses<<<dim3(BATCH * NHEAD, 64), 256, 0, stream>>>(x, Wm, xt, masses);
  prep_wh<<<(DMODEL * DMODEL / 4) / 256, 256, 0, stream>>>(Wout, wh);
  invdist_kernel<<<dim3(SEQ / 64, SEQ / 64), 256, 0, stream>>>(pos, invd);
  attn_mfma_kernel<<<dim3(BATCH * NHEAD, SEQ / 64), 512, 0, stream>>>(
      xt, masses, invd, G, attnout);
  out_gemm_mfma<<<dim3(DMODEL / 64, (BATCH * SEQ) / 64), 256, 0, stream>>>(
      attnout, wh, out);
}

// Round 4
// 162.565 us; speedup vs baseline: 1.1495x; 1.1495x over previous
//
#include <hip/hip_runtime.h>
#include <hip/hip_bf16.h>

#define SEQ 2048
#define DMODEL 1024
#define NHEAD 16
#define HDIM 64
#define DPOS 64
#define BATCH 2

constexpr float EVENT_HORIZON = 1e-6f;
constexpr float MAX_FORCE = 50.0f;
constexpr float CURV = 0.15f;
constexpr float LOG2E = 1.44269504f;
// P = exp2(min(f,50)*log2e - S2), S2 = 39*log2e: e <= 2^15.87 = 59847 (fp16-safe),
// ratio-invariant under softmax normalization.
constexpr float SHIFT = 39.0f;

typedef __attribute__((ext_vector_type(8))) short frag8;        // 8 bf16/ushort
typedef __attribute__((ext_vector_type(4))) unsigned int uint4v;
typedef __attribute__((ext_vector_type(8))) _Float16 half8;     // 8 fp16
typedef __attribute__((ext_vector_type(2))) _Float16 half2t;    // 2 fp16
typedef __attribute__((ext_vector_type(4))) float frag4f;       // 4 fp32 (C/D)

union A8u { half8 v; half2t h[4]; };

__device__ inline short bfbits(float f) {
  __hip_bfloat16 h = __float2bfloat16(f);
  return *reinterpret_cast<short*>(&h);
}
__device__ inline float fbits(unsigned u) {
  union { unsigned u; float f; } c; c.u = u; return c.f;
}
__device__ inline half2t pkrtz(float a, float b) {
  return __builtin_bit_cast(half2t, __builtin_amdgcn_cvt_pkrtz(a, b));
}
// native 2^x, single v_exp_f32 (no hidden *log2e mul like __expf)
__device__ inline float exp2_fast(float x) {
  float r;
  asm("v_exp_f32 %0, %1" : "=v"(r) : "v"(x));
  return r;
}
// XOR swizzle in 16B units: row = 8 units (128B); b128 frag reads (fixed unit,
// 16 consecutive rows) and staging writes both cover banks <=2-way (free).
__device__ inline int swz(int row, int u) { return row * 8 + (u ^ (row & 7)); }

// ---------------------------------------------------------------------------
// Prep A (fused): transpose x -> xt[bh][d][j] fp16 AND masses[bh][s] =
// softplus(dot(x_row, W_mass[h])).
// ---------------------------------------------------------------------------
__global__ __launch_bounds__(256) void prep_xt_masses(
    const float* __restrict__ x, const float* __restrict__ Wm,
    _Float16* __restrict__ xt, float* __restrict__ masses) {
  int bh = blockIdx.x;           // b*16+h
  int h = bh & 15, b = bh >> 4;
  int t = threadIdx.x;
  int d = t & 63;
  int jg = (t >> 6) + (blockIdx.y << 2);   // j-group of 8, 0..255
  int j0 = jg * 8;
  const float* src = x + (size_t)(b * SEQ) * DMODEL + h * HDIM + d;
  float wmd = Wm[h * HDIM + d];
  half8 v;
  float fv[8];
#pragma unroll
  for (int jj = 0; jj < 8; ++jj) {
    float f = src[(size_t)(j0 + jj) * DMODEL];
    fv[jj] = f;
    v[jj] = (_Float16)f;
  }
  *(half8*)(xt + ((size_t)bh * HDIM + d) * SEQ + j0) = v;

  float msum = 0.f;
#pragma unroll
  for (int jj = 0; jj < 8; ++jj) {
    float s = fv[jj] * wmd;
#pragma unroll
    for (int off = 32; off; off >>= 1) s += __shfl_xor(s, off, 64);
    if (d == jj) msum = s;      // lane jj keeps row j0+jj's dot
  }
  if (d < 8) {
    float m = (msum > 20.f) ? msum : log1pf(expf(msum));
    masses[(size_t)bh * SEQ + j0 + d] = m;
  }
}

// ---------------------------------------------------------------------------
// Prep B: Wout fp32 -> fp16.
// ---------------------------------------------------------------------------
__global__ __launch_bounds__(256) void prep_wh(
    const float* __restrict__ Wout, _Float16* __restrict__ wh) {
  int i = blockIdx.x * 256 + threadIdx.x;
  float4 v = ((const float4*)Wout)[i];
  _Float16 o[4] = {(_Float16)v.x, (_Float16)v.y, (_Float16)v.z, (_Float16)v.w};
  *(float2*)(wh + 4 * (size_t)i) = *(float2*)o;
}

// ---------------------------------------------------------------------------
// Kernel 2: LDS-tiled distance kernel, bf16 output.
// ---------------------------------------------------------------------------
__global__ __launch_bounds__(256) void invdist_kernel(
    const float* __restrict__ pos, unsigned short* __restrict__ invd) {
  __shared__ float Li[64 * 68];
  __shared__ float Lj[64 * 68];
  int t = threadIdx.x;
  int i0 = blockIdx.y * 64, j0 = blockIdx.x * 64;

  int kk = (t & 15) * 4;
  int rr = t >> 4;
#pragma unroll
  for (int q = 0; q < 4; ++q) {
    int row = q * 16 + rr;
    float4 a = *(const float4*)(pos + (size_t)(i0 + row) * DPOS + kk);
    float4 b = *(const float4*)(pos + (size_t)(j0 + row) * DPOS + kk);
    Li[(kk + 0) * 68 + row] = a.x; Li[(kk + 1) * 68 + row] = a.y;
    Li[(kk + 2) * 68 + row] = a.z; Li[(kk + 3) * 68 + row] = a.w;
    Lj[(kk + 0) * 68 + row] = b.x; Lj[(kk + 1) * 68 + row] = b.y;
    Lj[(kk + 2) * 68 + row] = b.z; Lj[(kk + 3) * 68 + row] = b.w;
  }
  __syncthreads();

  int ti = (t >> 4) * 4;
  int tj = (t & 15) * 4;

  float acc[4][4];
#pragma unroll
  for (int a = 0; a < 4; ++a)
#pragma unroll
    for (int b = 0; b < 4; ++b) acc[a][b] = 0.f;

#pragma unroll 8
  for (int k = 0; k < 64; ++k) {
    float4 a = *(const float4*)(&Li[k * 68 + ti]);
    float4 b = *(const float4*)(&Lj[k * 68 + tj]);
    float av[4] = {a.x, a.y, a.z, a.w};
    float bv[4] = {b.x, b.y, b.z, b.w};
#pragma unroll
    for (int mi = 0; mi < 4; ++mi)
#pragma unroll
      for (int mj = 0; mj < 4; ++mj) {
        float d = av[mi] - bv[mj];
        acc[mi][mj] += d * d;
      }
  }

#pragma unroll
  for (int mi = 0; mi < 4; ++mi) {
    ushort4 o;
    unsigned short* op = (unsigned short*)&o;
#pragma unroll
    for (int mj = 0; mj < 4; ++mj) {
      float d2 = acc[mi][mj];
      float dn = sqrtf(d2 + EVENT_HORIZON);
      float w = d2 * (1.f + CURV * __cosf(dn));
      op[mj] = (unsigned short)bfbits(1.0f / fmaxf(w, EVENT_HORIZON));
    }
    *(ushort4*)(&invd[(size_t)(i0 + ti + mi) * SEQ + j0 + tj]) = o;
  }
}

// ---------------------------------------------------------------------------
// Kernel 3: fused gravitational attention, fp16 MFMA PV.
// r4: occupancy via SMALL blocks, not j-split. Block = 256 thr = 4 waves x
// 16 i-rows = 64 i-rows; each wave sweeps the FULL 2048 j (no partial-sum
// combine, no epilogue exchange). Grid = 1024 blocks, 1D, XCD-clustered
// decode: bh = (bid&7)*4 + ((bid>>3)&3), iblk = bid>>5 (bijective) -> each
// XCD's L2 serves only 4 bh worth of xt/invd. launch_bounds(256,6) caps
// VGPR ~85 (r2's register discipline needs ~75 -> no spill, unlike r3's
// (512,8) which forced 32+scratch). LDS 16.5 KB -> 6-8 blocks/CU.
// ---------------------------------------------------------------------------
__global__ __launch_bounds__(256, 6) void attn_mfma_kernel(
    const _Float16* __restrict__ xt, const float* __restrict__ masses,
    const unsigned short* __restrict__ invd, const float* __restrict__ G,
    _Float16* __restrict__ attnout) {
  __shared__ _Float16 Vs[2][64 * 64];   // [buf], 8 KB each, XOR-swizzled
  __shared__ float Ms[2][64];           // masses chunk broadcast

  constexpr float S2 = SHIFT * LOG2E;                 // 56.265
  constexpr float C2 = (MAX_FORCE - SHIFT) * LOG2E;   // 15.870

  int bid = blockIdx.x;
  int bh = (bid & 7) * 4 + ((bid >> 3) & 3);   // XCD-clustered: 4 bh per XCD
  int iblk = bid >> 5;
  int h = bh & (NHEAD - 1), b = bh >> 4;
  int i0 = iblk * 64;
  int t = threadIdx.x, w = t >> 6, lane = t & 63;
  int l15 = lane & 15, quad = lane >> 4;
  int iw = i0 + w * 16;

  float gabs = fabsf(G[h]);
  const float* mrow = masses + (size_t)bh * SEQ;
  float cm = gabs * mrow[iw + l15] * LOG2E;           // row scalar, log2 domain
  const unsigned short* ivrow = invd + (size_t)(iw + l15) * SEQ;

  // staging role: thread t -> d-row t>>2, 16B-units {2*(t&3), 2*(t&3)+1}
  int srow = t >> 2, sunit = (t & 3) * 2;
  const _Float16* srcrow =
      xt + ((size_t)bh * HDIM + srow) * SEQ + sunit * 8;
  int swzoff0 = swz(srow, sunit) * 8;
  int swzoff1 = swz(srow, sunit + 1) * 8;

  half8 vone;
#pragma unroll
  for (int k = 0; k < 8; ++k) vone[k] = (_Float16)1.f;

  frag4f acc[4];
#pragma unroll
  for (int nt = 0; nt < 4; ++nt) acc[nt] = (frag4f)0.f;
  frag4f accs = (frag4f)0.f;          // row sums (every column identical)

  // ---- prologue: chunk 0 ----
  *(half8*)(&Vs[0][0] + swzoff0) = *(const half8*)(srcrow);
  *(half8*)(&Vs[0][0] + swzoff1) = *(const half8*)(srcrow + 8);
  if (t < 64) Ms[0][t] = mrow[t];
  frag8 iv_cur[2], iv_nxt[2];
  iv_cur[0] = *(const frag8*)(ivrow + quad * 8);
  iv_cur[1] = *(const frag8*)(ivrow + 32 + quad * 8);
  __syncthreads();

  for (int c = 0; c < 32; ++c) {
    // ---- issue prefetches for chunk c+1 (latency hidden by compute) ----
    half8 vpre0, vpre1;
    float mload = 0.f;
    if (c < 31) {
      int jn = (c + 1) * 64;
      vpre0 = *(const half8*)(srcrow + jn);
      vpre1 = *(const half8*)(srcrow + jn + 8);
      if (t < 64) mload = mrow[jn + t];
      iv_nxt[0] = *(const frag8*)(ivrow + jn + quad * 8);
      iv_nxt[1] = *(const frag8*)(ivrow + jn + 32 + quad * 8);
    }

    // ---- compute chunk c from buf[c&1] ----
    const _Float16* Vbase = &Vs[c & 1][0];
    const float* Mbase = &Ms[c & 1][0];

#pragma unroll
    for (int kh = 0; kh < 2; ++kh) {
      // masses broadcast from LDS (same addr across l15 -> bank broadcast)
      const float* mp = Mbase + kh * 32 + quad * 8;
      float4 mjl = *(const float4*)(mp);
      float4 mjh = *(const float4*)(mp + 4);
      float mjf[8] = {mjl.x, mjl.y, mjl.z, mjl.w,
                      mjh.x, mjh.y, mjh.z, mjh.w};
      uint4v uv = __builtin_bit_cast(uint4v, iv_cur[kh]);
      float e[8];
#pragma unroll
      for (int p = 0; p < 4; ++p) {
        float ivA = fbits(uv[p] << 16);          // even j: low bf16
        float ivB = fbits(uv[p] & 0xffff0000u);  // odd j: high bf16
        float fA = fmaf(cm * mjf[2 * p], ivA, -S2);
        float fB = fmaf(cm * mjf[2 * p + 1], ivB, -S2);
        e[2 * p] = exp2_fast(fminf(fA, C2));
        e[2 * p + 1] = exp2_fast(fminf(fB, C2));
      }
      A8u A;
#pragma unroll
      for (int p = 0; p < 4; ++p)
        A.h[p] = pkrtz(e[2 * p], e[2 * p + 1]);

      __builtin_amdgcn_s_setprio(1);
      accs = __builtin_amdgcn_mfma_f32_16x16x32_f16(A.v, vone, accs, 0, 0, 0);
#pragma unroll
      for (int nt = 0; nt < 4; ++nt) {
        half8 Bf = *(const half8*)(Vbase + swz(nt * 16 + l15, kh * 4 + quad) * 8);
        acc[nt] = __builtin_amdgcn_mfma_f32_16x16x32_f16(A.v, Bf, acc[nt], 0, 0, 0);
      }
      __builtin_amdgcn_s_setprio(0);
    }

    // ---- rotate prefetches in; write V/M prefetch to other buffer ----
    if (c < 31) {
      _Float16* Vn = &Vs[(c + 1) & 1][0];
      *(half8*)(Vn + swzoff0) = vpre0;
      *(half8*)(Vn + swzoff1) = vpre1;
      if (t < 64) Ms[(c + 1) & 1][t] = mload;
      iv_cur[0] = iv_nxt[0]; iv_cur[1] = iv_nxt[1];
    }
    __syncthreads();
  }

  // ---- normalize + store (accs[reg] already holds row r = quad*4+reg) ----
#pragma unroll
  for (int reg = 0; reg < 4; ++reg) {
    int r = quad * 4 + reg;            // C/D row within 16x16 tile
    float s = 1.f / accs[reg];
#pragma unroll
    for (int nt = 0; nt < 4; ++nt) {
      attnout[(size_t)(b * SEQ + iw + r) * DMODEL + h * HDIM + nt * 16 + l15] =
          (_Float16)(acc[nt][reg] * s);
    }
  }
}

// ---------------------------------------------------------------------------
// Kernel 4: out = attnout @ wh^T via fp16 MFMA. 128(M)x64(N) tile, BK=64,
// double-buffered swizzled LDS, one barrier per K-chunk. 4 waves, each
// 64m x 32n (4x2 frags). grid (16,32) = 512 blocks.
// ---------------------------------------------------------------------------
__global__ __launch_bounds__(256) void out_gemm_mfma(
    const _Float16* __restrict__ Ag, const _Float16* __restrict__ Wg,
    float* __restrict__ C) {
  __shared__ _Float16 As[2][128 * 64];   // 16 KB each
  __shared__ _Float16 Bs[2][64 * 64];    // 8 KB each

  int t = threadIdx.x, w = t >> 6, lane = t & 63;
  int l15 = lane & 15, quad = lane >> 4;
  int m0 = blockIdx.y * 128, n0 = blockIdx.x * 64;
  int mh = (w & 1) * 64, nh = (w >> 1) * 32;

  int ar = t >> 1;  int aku = (t & 1) * 4;
  int br = t >> 2;  int bku = (t & 3) * 2;
  const _Float16* abase = Ag + (size_t)(m0 + ar) * DMODEL + aku * 8;
  const _Float16* bbase = Wg + (size_t)(n0 + br) * DMODEL + bku * 8;

  frag4f acc[4][2];
#pragma unroll
  for (int mt = 0; mt < 4; ++mt)
#pragma unroll
    for (int nt = 0; nt < 2; ++nt) acc[mt][nt] = (frag4f)0.f;

  half8 a0, a1, a2, a3, b0, b1;
  a0 = *(const half8*)(abase);      a1 = *(const half8*)(abase + 8);
  a2 = *(const half8*)(abase + 16); a3 = *(const half8*)(abase + 24);
  b0 = *(const half8*)(bbase);      b1 = *(const half8*)(bbase + 8);
  {
    _Float16* aw = As[0]; _Float16* bw = Bs[0];
    *(half8*)(aw + swz(ar, aku + 0) * 8) = a0;
    *(half8*)(aw + swz(ar, aku + 1) * 8) = a1;
    *(half8*)(aw + swz(ar, aku + 2) * 8) = a2;
    *(half8*)(aw + swz(ar, aku + 3) * 8) = a3;
    *(half8*)(bw + swz(br, bku + 0) * 8) = b0;
    *(half8*)(bw + swz(br, bku + 1) * 8) = b1;
  }
  __syncthreads();

  for (int kc = 0; kc < 16; ++kc) {
    if (kc < 15) {
      const _Float16* ap = abase + (kc + 1) * 64;
      const _Float16* bp = bbase + (kc + 1) * 64;
      a0 = *(const half8*)(ap);      a1 = *(const half8*)(ap + 8);
      a2 = *(const half8*)(ap + 16); a3 = *(const half8*)(ap + 24);
      b0 = *(const half8*)(bp);      b1 = *(const half8*)(bp + 8);
    }

    const _Float16* ac = As[kc & 1];
    const _Float16* bc = Bs[kc & 1];
#pragma unroll
    for (int kh = 0; kh < 2; ++kh) {
      half8 Af[4], Bf[2];
#pragma unroll
      for (int mt = 0; mt < 4; ++mt)
        Af[mt] = *(const half8*)(ac + swz(mh + mt * 16 + l15, kh * 4 + quad) * 8);
#pragma unroll
      for (int nt = 0; nt < 2; ++nt)
        Bf[nt] = *(const half8*)(bc + swz(nh + nt * 16 + l15, kh * 4 + quad) * 8);
#pragma unroll
      for (int mt = 0; mt < 4; ++mt)
#pragma unroll
        for (int nt = 0; nt < 2; ++nt)
          acc[mt][nt] = __builtin_amdgcn_mfma_f32_16x16x32_f16(Af[mt], Bf[nt], acc[mt][nt], 0, 0, 0);
    }

    if (kc < 15) {
      _Float16* aw = As[(kc + 1) & 1]; _Float16* bw = Bs[(kc + 1) & 1];
      *(half8*)(aw + swz(ar, aku + 0) * 8) = a0;
      *(half8*)(aw + swz(ar, aku + 1) * 8) = a1;
      *(half8*)(aw + swz(ar, aku + 2) * 8) = a2;
      *(half8*)(aw + swz(ar, aku + 3) * 8) = a3;
      *(half8*)(bw + swz(br, bku + 0) * 8) = b0;
      *(half8*)(bw + swz(br, bku + 1) * 8) = b1;
    }
    __syncthreads();
  }

#pragma unroll
  for (int mt = 0; mt < 4; ++mt)
#pragma unroll
    for (int nt = 0; nt < 2; ++nt)
#pragma unroll
      for (int reg = 0; reg < 4; ++reg) {
        int m = m0 + mh + mt * 16 + quad * 4 + reg;
        int n = n0 + nh + nt * 16 + l15;
        C[(size_t)m * DMODEL + n] = acc[mt][nt][reg];
      }
}

// ---------------------------------------------------------------------------
extern "C" void kernel_launch(void* const* d_in, const int* in_sizes, int n_in,
                              void* d_out, int out_size, void* d_ws, size_t ws_size,
                              hipStream_t stream) {
  const float* x    = (const float*)d_in[0];
  const float* pos  = (const float*)d_in[1];
  const float* Wm   = (const float*)d_in[2];
  const float* G    = (const float*)d_in[3];
  const float* Wout = (const float*)d_in[4];
  float* out = (float*)d_out;

  char* wsb = (char*)d_ws;
  float* masses = (float*)wsb;                                    // 256 KB
  unsigned short* invd = (unsigned short*)(wsb + (1 << 18));      // 8 MB
  _Float16* attnout = (_Float16*)(wsb + (1 << 18) + (8 << 20));   // 8 MB
  _Float16* xt      = (_Float16*)(wsb + (1 << 18) + (16 << 20));  // 8 MB
  _Float16* wh      = (_Float16*)(wsb + (1 << 18) + (24 << 20));  // 2 MB

  prep_xt_masses<<<dim3(BATCH * NHEAD, 64), 256, 0, stream>>>(x, Wm, xt, masses);
  prep_wh<<<(DMODEL * DMODEL / 4) / 256, 256, 0, stream>>>(Wout, wh);
  invdist_kernel<<<dim3(SEQ / 64, SEQ / 64), 256, 0, stream>>>(pos, invd);
  attn_mfma_kernel<<<dim3(BATCH * NHEAD * (SEQ / 64)), 256, 0, stream>>>(
      xt, masses, invd, G, attnout);
  out_gemm_mfma<<<dim3(DMODEL / 64, (BATCH * SEQ) / 128), 256, 0, stream>>>(
      attnout, wh, out);
}